// Round 7
// baseline (2511.409 us; speedup 1.0000x reference)
//
#include <hip/hip_runtime.h>

// R=2048, S=64, V=8. One 64-lane wave per block = 8 points (t) x 8 views (v),
// lane = t*8+v. k-outer MLP loops: accumulators acc[o] are STATIC-indexed
// (inner o fully unrolled) -> stay in VGPRs; per-lane activations live in LDS
// as [feat][lane] (runtime feat index is legal in LDS; lane-stride-1 = no bank
// conflicts; 1 ds_read_b32 feeds 64 FMAs). Weight indices are wave-uniform ->
// scalar loads. No runtime indexing into register arrays anywhere (R5's bug:
// it demoted activations to scratch -> 1.1 GB of spill traffic).

#define NRS (2048*64)

__device__ __forceinline__ float eluf(float x){ return x > 0.f ? x : __expf(x)-1.f; }
__device__ __forceinline__ float sigmf(float x){ return 1.f/(1.f+__expf(-x)); }
__device__ __forceinline__ float sum8(float x){
    x += __shfl_xor(x,1); x += __shfl_xor(x,2); x += __shfl_xor(x,4); return x;
}
__device__ __forceinline__ float max8(float x){
    x = fmaxf(x,__shfl_xor(x,1)); x = fmaxf(x,__shfl_xor(x,2)); x = fmaxf(x,__shfl_xor(x,4)); return x;
}

__global__ __launch_bounds__(64, 1) void nerf_main(
    const float* __restrict__ g_rgb,  const float* __restrict__ g_nr,
    const float* __restrict__ g_rd,   const float* __restrict__ g_mask,
    const float* __restrict__ rd_w1,  const float* __restrict__ rd_b1,
    const float* __restrict__ rd_w2,  const float* __restrict__ rd_b2,
    const float* __restrict__ rf_w1,  const float* __restrict__ rf_b1,
    const float* __restrict__ rf_w2,  const float* __restrict__ rf_b2,
    const float* __restrict__ nr_w1,  const float* __restrict__ nr_b1,
    const float* __restrict__ nr_w2,  const float* __restrict__ nr_b2,
    const float* __restrict__ base_w1,const float* __restrict__ base_b1,
    const float* __restrict__ base_w2,const float* __restrict__ base_b2,
    const float* __restrict__ vis_w1, const float* __restrict__ vis_b1,
    const float* __restrict__ vis_w2, const float* __restrict__ vis_b2,
    const float* __restrict__ v2_w1,  const float* __restrict__ v2_b1,
    const float* __restrict__ v2_w2,  const float* __restrict__ v2_b2,
    float* __restrict__ out)
{
    // Aliased LDS pool (floats). Lifetimes verified disjoint per region:
    //  ACT  @0    [64][64]=4096 : rf1-out -> rf2 | g[8][144] (fmv->gc) | base1-out -> base2
    //  RGB  @4096 [35][64]=2240 : rgb/rgb_feat_ (->base1) | hv[32][64] (vis/v2) | out-stage[512]
    //  NR   @6336 [32][64]=2048 : neuray (->base1) | x2[32][64] (base2-out -> end)
    //  GC   @8384 [8][65]=520   : globalfeat partial of base-l1
    //  GMAX @8904 [8][65]=520   : rgb_feat_max
    __shared__ __align__(16) float S[9424];
    float* const s_act  = S;
    float* const s_rgb  = S + 4096;
    float* const s_nr   = S + 6336;
    float* const s_gc   = S + 8384;
    float* const s_gmax = S + 8904;

    const int lane = threadIdx.x;      // 0..63
    const int t    = lane >> 3;        // point in block
    const int v    = lane & 7;         // view
    const int pid  = blockIdx.x * 64 + lane;

    // ---- P0: inputs ----
    #pragma unroll 1
    for (int k = 0; k < 35; ++k) s_rgb[k*64 + lane] = g_rgb[(size_t)pid*35 + k];
    #pragma unroll 1
    for (int k = 0; k < 32; ++k) s_nr[k*64 + lane] = g_nr[(size_t)pid*32 + k];
    float rdv[4];
    #pragma unroll
    for (int k = 0; k < 4; ++k) rdv[k] = g_rd[(size_t)pid*4 + k];
    const float mask = g_mask[pid];
    const float wt   = mask / (sum8(mask) + 1e-8f);

    // ---- P1: rf layer1 (k-outer; acc static; xk via ds_read) ----
    {
        float acc[64];
        #pragma unroll
        for (int o = 0; o < 64; ++o) acc[o] = rf_b1[o];
        #pragma unroll 2
        for (int k = 0; k < 35; ++k) {
            const float xk = s_rgb[k*64 + lane];
            #pragma unroll
            for (int o = 0; o < 64; ++o) acc[o] = fmaf(xk, rf_w1[k*64 + o], acc[o]);
        }
        #pragma unroll
        for (int o = 0; o < 64; ++o) s_act[o*64 + lane] = fmaxf(acc[o], 0.f);
    }

    // ---- P2: rf layer2 -> gmax over views (no need to store outputs) ----
    {
        float acc[64];
        #pragma unroll
        for (int o = 0; o < 64; ++o) acc[o] = rf_b2[o];
        #pragma unroll 2
        for (int k = 0; k < 64; ++k) {
            const float xk = s_act[k*64 + lane];
            #pragma unroll
            for (int o = 0; o < 64; ++o) acc[o] = fmaf(xk, rf_w2[k*64 + o], acc[o]);
        }
        #pragma unroll
        for (int o = 0; o < 64; ++o) {
            const float gm = max8(acc[o]);
            if (v == (o & 7)) s_gmax[t*65 + o] = gm;
        }
    }

    // ---- P3: rd MLP (regs fully static) -> rgb_feat_ in place in LDS ----
    {
        float h16[16];
        #pragma unroll
        for (int o = 0; o < 16; ++o) {
            float a = rd_b1[o];
            #pragma unroll
            for (int k = 0; k < 4; ++k) a = fmaf(rdv[k], rd_w1[k*16 + o], a);
            h16[o] = eluf(a);
        }
        #pragma unroll 1
        for (int o = 0; o < 35; ++o) {
            float a = rd_b2[o];
            #pragma unroll
            for (int k = 0; k < 16; ++k) a = fmaf(h16[k], rd_w2[k*35 + o], a);
            s_rgb[o*64 + lane] += eluf(a);       // s_rgb is now rgb_feat_
        }
    }

    // ---- P4: nr MLP -> weight0 ----
    float w0;
    {
        float h8[8];
        #pragma unroll
        for (int o = 0; o < 8; ++o) h8[o] = nr_b1[o];
        #pragma unroll 2
        for (int k = 0; k < 32; ++k) {
            const float xk = s_nr[k*64 + lane];
            #pragma unroll
            for (int o = 0; o < 8; ++o) h8[o] = fmaf(xk, nr_w1[k*8 + o], h8[o]);
        }
        float a = nr_b2[0];
        #pragma unroll
        for (int k = 0; k < 8; ++k) a = fmaf(eluf(h8[k]), nr_w2[k], a);
        w0 = sigmf(a);
    }

    // ---- P5: fmv (two-pass) -> globalfeat g[t][140] in ACT region ----
    #pragma unroll 1
    for (int f = 0; f < 35; ++f) {
        const float a  = s_rgb[f*64 + lane];
        const float m0 = sum8(w0 * a);
        const float d0 = a - m0;
        const float v0 = sum8(w0 * d0 * d0);
        const float m1 = sum8(wt * a);
        const float d1 = a - m1;
        const float v1 = sum8(wt * d1 * d1);
        if (v == (f & 7)) {
            s_act[t*144 + f]       = m0;
            s_act[t*144 + 35 + f]  = v0;
            s_act[t*144 + 70 + f]  = m1;
            s_act[t*144 + 105 + f] = v1;
        }
    }
    __syncthreads();

    // ---- P6: globalfeat part of base-l1 (lane = output o; all 8 t's) ----
    {
        float ga[8];
        #pragma unroll
        for (int q = 0; q < 8; ++q) ga[q] = 0.f;
        #pragma unroll 1
        for (int i = 0; i < 140; i += 4) {
            float w_[4];
            #pragma unroll
            for (int j = 0; j < 4; ++j) w_[j] = base_w1[(i + j)*64 + lane];
            #pragma unroll
            for (int q = 0; q < 8; ++q) {
                const float4 gv = *reinterpret_cast<const float4*>(&s_act[q*144 + i]);
                ga[q] = fmaf(gv.x, w_[0], ga[q]);
                ga[q] = fmaf(gv.y, w_[1], ga[q]);
                ga[q] = fmaf(gv.z, w_[2], ga[q]);
                ga[q] = fmaf(gv.w, w_[3], ga[q]);
            }
        }
        #pragma unroll
        for (int q = 0; q < 8; ++q) s_gc[q*65 + lane] = ga[q];
    }
    __syncthreads();

    // ---- P7: base layer1 (view part) -> ACT region (overwrites g) ----
    {
        float acc[64];
        #pragma unroll
        for (int o = 0; o < 64; ++o) acc[o] = base_b1[o] + s_gc[t*65 + o];
        #pragma unroll 2
        for (int k = 0; k < 35; ++k) {
            const float xk = s_rgb[k*64 + lane];
            #pragma unroll
            for (int o = 0; o < 64; ++o) acc[o] = fmaf(xk, base_w1[(140+k)*64 + o], acc[o]);
        }
        #pragma unroll 2
        for (int k = 0; k < 32; ++k) {
            const float xk = s_nr[k*64 + lane];
            #pragma unroll
            for (int o = 0; o < 64; ++o) acc[o] = fmaf(xk, base_w1[(175+k)*64 + o], acc[o]);
        }
        #pragma unroll
        for (int o = 0; o < 64; ++o) s_act[o*64 + lane] = eluf(acc[o]);
    }

    // ---- P8: base layer2 -> x2 into NR region (neuray dead) ----
    {
        float acc[32];
        #pragma unroll
        for (int o = 0; o < 32; ++o) acc[o] = base_b2[o];
        #pragma unroll 2
        for (int k = 0; k < 64; ++k) {
            const float xk = s_act[k*64 + lane];
            #pragma unroll
            for (int o = 0; o < 32; ++o) acc[o] = fmaf(xk, base_w2[k*32 + o], acc[o]);
        }
        #pragma unroll
        for (int o = 0; o < 32; ++o) s_nr[o*64 + lane] = eluf(acc[o]);   // x2
    }

    // ---- P9: vis layer1 (x*wt hoisted) -> hv into RGB region (rgb dead) ----
    {
        float acc[32];
        #pragma unroll
        for (int o = 0; o < 32; ++o) acc[o] = 0.f;
        #pragma unroll 2
        for (int k = 0; k < 32; ++k) {
            const float xk = s_nr[k*64 + lane];
            #pragma unroll
            for (int o = 0; o < 32; ++o) acc[o] = fmaf(xk, vis_w1[k*32 + o], acc[o]);
        }
        #pragma unroll
        for (int o = 0; o < 32; ++o)
            s_rgb[o*64 + lane] = eluf(fmaf(acc[o], wt, vis_b1[o]));      // hv
    }

    // ---- P10: vis layer2 -> x2 += x_res; vis channel ----
    float vis1;
    {
        float acc[32];
        #pragma unroll
        for (int o = 0; o < 32; ++o) acc[o] = vis_b2[o];
        float a2 = vis_b2[32];
        #pragma unroll 2
        for (int k = 0; k < 32; ++k) {
            const float hk = s_rgb[k*64 + lane];
            #pragma unroll
            for (int o = 0; o < 32; ++o) acc[o] = fmaf(hk, vis_w2[k*33 + o], acc[o]);
            a2 = fmaf(hk, vis_w2[k*33 + 32], a2);
        }
        #pragma unroll
        for (int o = 0; o < 32; ++o) s_nr[o*64 + lane] += eluf(acc[o]);  // x = x + x_res
        vis1 = sigmf(eluf(a2)) * mask;
    }

    // ---- P11: v2 layer1 (x*vis1 hoisted) -> hv2 into RGB region ----
    {
        float acc[32];
        #pragma unroll
        for (int o = 0; o < 32; ++o) acc[o] = 0.f;
        #pragma unroll 2
        for (int k = 0; k < 32; ++k) {
            const float xk = s_nr[k*64 + lane];
            #pragma unroll
            for (int o = 0; o < 32; ++o) acc[o] = fmaf(xk, v2_w1[k*32 + o], acc[o]);
        }
        #pragma unroll
        for (int o = 0; o < 32; ++o)
            s_rgb[o*64 + lane] = eluf(fmaf(acc[o], vis1, v2_b1[o]));     // hv2
    }

    // ---- P12: v2 layer2 (scalar out) -> vis2 ----
    float vis2;
    {
        float a = v2_b2[0];
        #pragma unroll 2
        for (int k = 0; k < 32; ++k) a = fmaf(s_rgb[k*64 + lane], v2_w2[k], a);
        vis2 = sigmf(a) * mask;
    }
    __syncthreads();

    // ---- P13: final fmv + gmax -> stage into RGB region (hv2 dead) ----
    {
        const float w2 = vis2 / (sum8(vis2) + 1e-8f);
        #pragma unroll 1
        for (int c = 0; c < 32; ++c) {
            const float xv = s_nr[c*64 + lane];      // x2
            const float m  = sum8(w2 * xv);
            const float d  = xv - m;
            const float va = sum8(w2 * d * d);
            if (v == (c & 7)) {
                s_rgb[t*64 + c]      = m  + s_gmax[t*65 + c];
                s_rgb[t*64 + 32 + c] = va + s_gmax[t*65 + 32 + c];
            }
        }
    }
    __syncthreads();

    // ---- P14: coalesced output (512 contiguous floats per block) ----
    const size_t ob = (size_t)blockIdx.x * 512;
    #pragma unroll
    for (int j = 0; j < 8; ++j)
        out[ob + j*64 + lane] = s_rgb[j*64 + lane];
}

extern "C" void kernel_launch(void* const* d_in, const int* in_sizes, int n_in,
                              void* d_out, int out_size, void* d_ws, size_t ws_size,
                              hipStream_t stream) {
    const float* g_rgb   = (const float*)d_in[0];
    const float* g_nr    = (const float*)d_in[1];
    const float* g_rd    = (const float*)d_in[2];
    const float* g_mask  = (const float*)d_in[3];
    // d_in[4] que_pts, d_in[5] que_dir: unused by the reference
    const float* rd_w1   = (const float*)d_in[6];
    const float* rd_b1   = (const float*)d_in[7];
    const float* rd_w2   = (const float*)d_in[8];
    const float* rd_b2   = (const float*)d_in[9];
    const float* rf_w1   = (const float*)d_in[10];
    const float* rf_b1   = (const float*)d_in[11];
    const float* rf_w2   = (const float*)d_in[12];
    const float* rf_b2   = (const float*)d_in[13];
    const float* nr_w1   = (const float*)d_in[14];
    const float* nr_b1   = (const float*)d_in[15];
    const float* nr_w2   = (const float*)d_in[16];
    const float* nr_b2   = (const float*)d_in[17];
    const float* base_w1 = (const float*)d_in[18];
    const float* base_b1 = (const float*)d_in[19];
    const float* base_w2 = (const float*)d_in[20];
    const float* base_b2 = (const float*)d_in[21];
    const float* vis_w1  = (const float*)d_in[22];
    const float* vis_b1  = (const float*)d_in[23];
    const float* vis_w2  = (const float*)d_in[24];
    const float* vis_b2  = (const float*)d_in[25];
    const float* v2_w1   = (const float*)d_in[26];
    const float* v2_b1   = (const float*)d_in[27];
    const float* v2_w2   = (const float*)d_in[28];
    const float* v2_b2   = (const float*)d_in[29];
    float* out = (float*)d_out;

    hipLaunchKernelGGL(nerf_main, dim3(NRS / 8), dim3(64), 0, stream,
        g_rgb, g_nr, g_rd, g_mask,
        rd_w1, rd_b1, rd_w2, rd_b2,
        rf_w1, rf_b1, rf_w2, rf_b2,
        nr_w1, nr_b1, nr_w2, nr_b2,
        base_w1, base_b1, base_w2, base_b2,
        vis_w1, vis_b1, vis_w2, vis_b2,
        v2_w1, v2_b1, v2_w2, v2_b2,
        out);
}

// Round 11
// 1631.861 us; speedup vs baseline: 1.5390x; 1.5390x over previous
//
#include <hip/hip_runtime.h>

// R=2048, S=64, V=8. One 64-lane wave per block = 16 view-points (2 rays x 8
// views). Lane = output neuron o. Weights pre-packed k4-major/lane-minor in
// d_ws: W'[k4][o][4] -> a wave's weight load is one contiguous 1KB block
// (8 cache lines, coalesced) on the vmcnt pipe. Activations: LDS x[k4][p][4]
// (stride 84 floats, b128-aligned), wave-uniform broadcast ds_read_b128
// (1 LDS op : 4 FMA-instrs). Accumulators fully static. Single wave, no barriers.

#define NRS  (2048*64)
#define NBLK (NRS/2)          // 2 rays (16 view-points) per block

// LDS float offsets
#define X_RGB 0               // [9][16][4] stride 84 (k=0..34, pad 35)
#define X_NR  756             // [8][16][4] stride 84
#define X_ACT 1428            // [16][16][4] stride 84
#define X_H16 2772            // [4][16][4] stride 84 (rd hidden)
#define X_RD  3108            // [4][16] flat
#define X_G   3172            // g[2][144]
#define X_X2  3460            // [8][16][4] stride 84
#define X_HV  4132            // [8][16][4] stride 84
#define X_GMX 4804            // [2][64]
#define SC_MASK 4932
#define SC_WT   4948
#define SC_W0   4964
#define SC_V1   4980
#define SC_V2   4996
#define LDS_TOT 5012

// d_ws float offsets — k4-major, lane-minor blocks: W'[k4][lane][4]
#define WT_RF1 0              // [9][64][4]   rf_w1^T   (k pad 35->0)
#define WT_RF2 2304           // [16][64][4]  rf_w2^T
#define WT_RD2 6400           // [4][64][4]   rd_w2^T   (o pad 35..63 ->0)
#define WT_B1G 7424           // [35][64][4]  base_w1 rows 0..139
#define WT_B1V 16384          // [17][64][4]  blocks 0..8: rgb rows 140..174(+pad); 9..16: nr rows 175..206
#define WT_B2  20736          // [16][32][4]  base_w2^T
#define WT_V1  22784          // [8][32][4]   vis_w1^T
#define WT_V2  23808          // [8][32][4]   vis_w2^T (first 32 cols)
#define WT_U1  24832          // [8][32][4]   v2_w1^T
#define WT_TOT 25856

__device__ __forceinline__ float eluf(float x){ return x > 0.f ? x : __expf(x)-1.f; }
__device__ __forceinline__ float sigmf(float x){ return 1.f/(1.f+__expf(-x)); }

__global__ __launch_bounds__(256) void transpose_w(
    const float* __restrict__ rf_w1, const float* __restrict__ rf_w2,
    const float* __restrict__ rd_w2, const float* __restrict__ base_w1,
    const float* __restrict__ base_w2, const float* __restrict__ vis_w1,
    const float* __restrict__ vis_w2, const float* __restrict__ v2_w1,
    float* __restrict__ ws)
{
    int i = blockIdx.x * 256 + threadIdx.x;
    if (i < WT_RF2) {                        // RF1 [9][64][4]
        int k4 = i >> 8, r = i & 255, o = r >> 2, j = r & 3, k = k4*4 + j;
        ws[i] = (k < 35) ? rf_w1[k*64 + o] : 0.f;
    } else if (i < WT_RD2) {                 // RF2 [16][64][4]
        int j2 = i - WT_RF2;
        int k4 = j2 >> 8, r = j2 & 255, o = r >> 2, j = r & 3, k = k4*4 + j;
        ws[i] = rf_w2[k*64 + o];
    } else if (i < WT_B1G) {                 // RD2 [4][64][4]
        int j2 = i - WT_RD2;
        int k4 = j2 >> 8, r = j2 & 255, o = r >> 2, j = r & 3, k = k4*4 + j;
        ws[i] = (o < 35) ? rd_w2[k*35 + o] : 0.f;
    } else if (i < WT_B1V) {                 // B1G [35][64][4]
        int j2 = i - WT_B1G;
        int k4 = j2 >> 8, r = j2 & 255, o = r >> 2, j = r & 3, k = k4*4 + j;
        ws[i] = base_w1[k*64 + o];
    } else if (i < WT_B2) {                  // B1V [17][64][4]
        int j2 = i - WT_B1V;
        int k4 = j2 >> 8, r = j2 & 255, o = r >> 2, j = r & 3;
        float v = 0.f;
        if (k4 < 9) { int k = k4*4 + j; if (k < 35) v = base_w1[(140 + k)*64 + o]; }
        else        { int k = (k4 - 9)*4 + j;       v = base_w1[(175 + k)*64 + o]; }
        ws[i] = v;
    } else if (i < WT_V1) {                  // B2 [16][32][4]
        int j2 = i - WT_B2;
        int k4 = j2 >> 7, r = j2 & 127, o = r >> 2, j = r & 3, k = k4*4 + j;
        ws[i] = base_w2[k*32 + o];
    } else if (i < WT_V2) {                  // V1 [8][32][4]
        int j2 = i - WT_V1;
        int k4 = j2 >> 7, r = j2 & 127, o = r >> 2, j = r & 3, k = k4*4 + j;
        ws[i] = vis_w1[k*32 + o];
    } else if (i < WT_U1) {                  // V2 [8][32][4]
        int j2 = i - WT_V2;
        int k4 = j2 >> 7, r = j2 & 127, o = r >> 2, j = r & 3, k = k4*4 + j;
        ws[i] = vis_w2[k*33 + o];
    } else if (i < WT_TOT) {                 // U1 [8][32][4]
        int j2 = i - WT_U1;
        int k4 = j2 >> 7, r = j2 & 127, o = r >> 2, j = r & 3, k = k4*4 + j;
        ws[i] = v2_w1[k*32 + o];
    }
}

__global__ __launch_bounds__(64, 2) void nerf_main(
    const float* __restrict__ g_rgb,  const float* __restrict__ g_nr,
    const float* __restrict__ g_rd,   const float* __restrict__ g_mask,
    const float* __restrict__ rd_w1,  const float* __restrict__ rd_b1,
    const float* __restrict__ rd_b2,
    const float* __restrict__ rf_b1,  const float* __restrict__ rf_b2,
    const float* __restrict__ nr_w1,  const float* __restrict__ nr_b1,
    const float* __restrict__ nr_w2,  const float* __restrict__ nr_b2,
    const float* __restrict__ base_b1,const float* __restrict__ base_b2,
    const float* __restrict__ vis_b1, const float* __restrict__ vis_w2,
    const float* __restrict__ vis_b2,
    const float* __restrict__ v2_b1,  const float* __restrict__ v2_w2,
    const float* __restrict__ v2_b2,
    const float* __restrict__ W,      // packed weights (d_ws)
    float* __restrict__ out)
{
    __shared__ __align__(16) float Sf[LDS_TOT];
    const int lane = threadIdx.x;                // 0..63
    const size_t b = blockIdx.x;

    // ================= staging =================
    {
        const float* src = g_rgb + b*560;
        #pragma unroll
        for (int it = 0; it < 9; ++it) {
            int idx = it*64 + lane;
            if (idx < 560) {
                int p = idx / 35, k = idx - p*35;
                Sf[X_RGB + (k>>2)*84 + p*4 + (k&3)] = src[idx];
            }
        }
        if (lane < 16) Sf[X_RGB + 8*84 + lane*4 + 3] = 0.f;   // zero pad k=35
        const float* srcn = g_nr + b*512;
        #pragma unroll
        for (int it = 0; it < 8; ++it) {
            int idx = it*64 + lane;
            int p = idx >> 5, k = idx & 31;
            Sf[X_NR + (k>>2)*84 + p*4 + (k&3)] = srcn[idx];
        }
        Sf[X_RD + (lane&3)*16 + (lane>>2)] = g_rd[b*64 + lane];
        if (lane < 16) {
            float m = g_mask[b*16 + lane];
            float s = m;
            s += __shfl_xor(s,1); s += __shfl_xor(s,2); s += __shfl_xor(s,4);
            Sf[SC_MASK + lane] = m;
            Sf[SC_WT   + lane] = m / (s + 1e-8f);
        }
    }

    // generic 64-out k4 step: acc[p] += dot(w4, x4[p])
#define STEP16(ACC, XBASE, W4) { \
        _Pragma("unroll") \
        for (int p = 0; p < 16; ++p) { \
            const float4 xv = *reinterpret_cast<const float4*>(&Sf[(XBASE) + p*4]); \
            ACC[p] = fmaf(xv.x, (W4).x, ACC[p]); \
            ACC[p] = fmaf(xv.y, (W4).y, ACC[p]); \
            ACC[p] = fmaf(xv.z, (W4).z, ACC[p]); \
            ACC[p] = fmaf(xv.w, (W4).w, ACC[p]); \
        } }

    // ================= rf layer1 (relu) : lane=o =================
    {
        float acc[16];
        const float bb = rf_b1[lane];
        #pragma unroll
        for (int p = 0; p < 16; ++p) acc[p] = bb;
        #pragma unroll 1
        for (int k4 = 0; k4 < 9; ++k4) {
            const float4 w4 = *reinterpret_cast<const float4*>(&W[WT_RF1 + k4*256 + lane*4]);
            STEP16(acc, X_RGB + k4*84, w4);
        }
        #pragma unroll
        for (int p = 0; p < 16; ++p)
            Sf[X_ACT + (lane>>2)*84 + p*4 + (lane&3)] = fmaxf(acc[p], 0.f);
    }

    // ================= rf layer2 -> gmax : lane=o =================
    {
        float acc[16];
        const float bb = rf_b2[lane];
        #pragma unroll
        for (int p = 0; p < 16; ++p) acc[p] = bb;
        #pragma unroll 1
        for (int k4 = 0; k4 < 16; ++k4) {
            const float4 w4 = *reinterpret_cast<const float4*>(&W[WT_RF2 + k4*256 + lane*4]);
            STEP16(acc, X_ACT + k4*84, w4);
        }
        float g0 = acc[0], g1 = acc[8];
        #pragma unroll
        for (int p = 1; p < 8; ++p) { g0 = fmaxf(g0, acc[p]); g1 = fmaxf(g1, acc[8+p]); }
        Sf[X_GMX + lane]      = g0;
        Sf[X_GMX + 64 + lane] = g1;
    }

    // ================= rd layer1 : lane=(p,og4) =================
    {
        const int p = lane >> 2, og4 = lane & 3;
        float4 h = *reinterpret_cast<const float4*>(&rd_b1[og4*4]);
        #pragma unroll
        for (int k = 0; k < 4; ++k) {
            const float xk = Sf[X_RD + k*16 + p];
            const float4 w4 = *reinterpret_cast<const float4*>(&rd_w1[k*16 + og4*4]);
            h.x = fmaf(xk, w4.x, h.x); h.y = fmaf(xk, w4.y, h.y);
            h.z = fmaf(xk, w4.z, h.z); h.w = fmaf(xk, w4.w, h.w);
        }
        h.x = eluf(h.x); h.y = eluf(h.y); h.z = eluf(h.z); h.w = eluf(h.w);
        *reinterpret_cast<float4*>(&Sf[X_H16 + og4*84 + p*4]) = h;
    }

    // ================= rd layer2 -> rgb_feat_ (in-place) : lane=o(<35) =================
    if (lane < 35) {
        float acc[16];
        const float bb = rd_b2[lane];
        #pragma unroll
        for (int p = 0; p < 16; ++p) acc[p] = bb;
        #pragma unroll 1
        for (int k4 = 0; k4 < 4; ++k4) {
            const float4 w4 = *reinterpret_cast<const float4*>(&W[WT_RD2 + k4*256 + lane*4]);
            STEP16(acc, X_H16 + k4*84, w4);
        }
        #pragma unroll
        for (int p = 0; p < 16; ++p) {
            const int idx = X_RGB + (lane>>2)*84 + p*4 + (lane&3);
            Sf[idx] += eluf(acc[p]);
        }
    }

    // ================= nr MLP -> weight0 : lane=(p,og) =================
    {
        const int p = lane >> 2, og = lane & 3;
        float h0 = nr_b1[og*2], h1 = nr_b1[og*2 + 1];
        #pragma unroll
        for (int k = 0; k < 32; ++k) {
            const float xk = Sf[X_NR + (k>>2)*84 + p*4 + (k&3)];
            const float2 w2 = *reinterpret_cast<const float2*>(&nr_w1[k*8 + og*2]);
            h0 = fmaf(xk, w2.x, h0); h1 = fmaf(xk, w2.y, h1);
        }
        const float2 v2 = *reinterpret_cast<const float2*>(&nr_w2[og*2]);
        float part = eluf(h0)*v2.x + eluf(h1)*v2.y;
        part += __shfl_xor(part, 1); part += __shfl_xor(part, 2);
        if (og == 0) Sf[SC_W0 + p] = sigmf(part + nr_b2[0]);
    }

    // ================= fmv -> g[2][140] : lane=f(<35) =================
    if (lane < 35) {
        float xf[16], w0v[16], wtv[16];
        #pragma unroll
        for (int p = 0; p < 16; ++p) {
            xf[p]  = Sf[X_RGB + (lane>>2)*84 + p*4 + (lane&3)];
            w0v[p] = Sf[SC_W0 + p];
            wtv[p] = Sf[SC_WT + p];
        }
        #pragma unroll
        for (int rs = 0; rs < 2; ++rs) {
            const int o8 = rs*8;
            float m0 = 0.f, m1 = 0.f;
            #pragma unroll
            for (int p = 0; p < 8; ++p) {
                m0 = fmaf(w0v[o8+p], xf[o8+p], m0);
                m1 = fmaf(wtv[o8+p], xf[o8+p], m1);
            }
            float v0 = 0.f, v1 = 0.f;
            #pragma unroll
            for (int p = 0; p < 8; ++p) {
                const float d0 = xf[o8+p] - m0, d1 = xf[o8+p] - m1;
                v0 = fmaf(w0v[o8+p]*d0, d0, v0);
                v1 = fmaf(wtv[o8+p]*d1, d1, v1);
            }
            Sf[X_G + rs*144 + lane]       = m0;
            Sf[X_G + rs*144 + 35 + lane]  = v0;
            Sf[X_G + rs*144 + 70 + lane]  = m1;
            Sf[X_G + rs*144 + 105 + lane] = v1;
        }
    }

    // ================= base-l1 global part : lane=o =================
    float gc0 = 0.f, gc1 = 0.f;
    {
        #pragma unroll 1
        for (int i4 = 0; i4 < 35; ++i4) {
            const float4 w4 = *reinterpret_cast<const float4*>(&W[WT_B1G + i4*256 + lane*4]);
            const float4 ga = *reinterpret_cast<const float4*>(&Sf[X_G + i4*4]);
            const float4 gb = *reinterpret_cast<const float4*>(&Sf[X_G + 144 + i4*4]);
            gc0 = fmaf(ga.x,w4.x, fmaf(ga.y,w4.y, fmaf(ga.z,w4.z, fmaf(ga.w,w4.w, gc0))));
            gc1 = fmaf(gb.x,w4.x, fmaf(gb.y,w4.y, fmaf(gb.z,w4.z, fmaf(gb.w,w4.w, gc1))));
        }
    }

    // ================= base-l1 view part : lane=o =================
    {
        float acc[16];
        const float bb = base_b1[lane];
        #pragma unroll
        for (int p = 0; p < 16; ++p) acc[p] = bb + (p < 8 ? gc0 : gc1);
        #pragma unroll 1
        for (int k4 = 0; k4 < 9; ++k4) {       // rgb_feat_ (incl zero pad)
            const float4 w4 = *reinterpret_cast<const float4*>(&W[WT_B1V + k4*256 + lane*4]);
            STEP16(acc, X_RGB + k4*84, w4);
        }
        #pragma unroll 1
        for (int k4 = 0; k4 < 8; ++k4) {       // neuray
            const float4 w4 = *reinterpret_cast<const float4*>(&W[WT_B1V + (9+k4)*256 + lane*4]);
            STEP16(acc, X_NR + k4*84, w4);
        }
        #pragma unroll
        for (int p = 0; p < 16; ++p)
            Sf[X_ACT + (lane>>2)*84 + p*4 + (lane&3)] = eluf(acc[p]);
    }

    // 32-out k4 step over half the points (h = lane>>5)
#define STEP8(ACC, XBASE, W4, H) { \
        _Pragma("unroll") \
        for (int p = 0; p < 8; ++p) { \
            const float4 xv = *reinterpret_cast<const float4*>(&Sf[(XBASE) + ((H)*8 + p)*4]); \
            ACC[p] = fmaf(xv.x, (W4).x, ACC[p]); \
            ACC[p] = fmaf(xv.y, (W4).y, ACC[p]); \
            ACC[p] = fmaf(xv.z, (W4).z, ACC[p]); \
            ACC[p] = fmaf(xv.w, (W4).w, ACC[p]); \
        } }

    const int o32 = lane & 31, hh = lane >> 5;

    // ================= base layer2 -> x2 : lane=(o,h) =================
    {
        float acc[8];
        const float bb = base_b2[o32];
        #pragma unroll
        for (int p = 0; p < 8; ++p) acc[p] = bb;
        #pragma unroll 1
        for (int k4 = 0; k4 < 16; ++k4) {
            const float4 w4 = *reinterpret_cast<const float4*>(&W[WT_B2 + k4*128 + o32*4]);
            STEP8(acc, X_ACT + k4*84, w4, hh);
        }
        #pragma unroll
        for (int p = 0; p < 8; ++p)
            Sf[X_X2 + (o32>>2)*84 + (hh*8+p)*4 + (o32&3)] = eluf(acc[p]);
    }

    // ================= vis layer1 (x*wt hoisted) -> hv =================
    {
        float acc[8];
        #pragma unroll
        for (int p = 0; p < 8; ++p) acc[p] = 0.f;
        #pragma unroll 1
        for (int k4 = 0; k4 < 8; ++k4) {
            const float4 w4 = *reinterpret_cast<const float4*>(&W[WT_V1 + k4*128 + o32*4]);
            STEP8(acc, X_X2 + k4*84, w4, hh);
        }
        const float bb = vis_b1[o32];
        #pragma unroll
        for (int p = 0; p < 8; ++p)
            Sf[X_HV + (o32>>2)*84 + (hh*8+p)*4 + (o32&3)] =
                eluf(fmaf(acc[p], Sf[SC_WT + hh*8 + p], bb));
    }

    // ================= vis layer2 main -> x2 += elu(res) =================
    {
        float acc[8];
        const float bb = vis_b2[o32];
        #pragma unroll
        for (int p = 0; p < 8; ++p) acc[p] = bb;
        #pragma unroll 1
        for (int k4 = 0; k4 < 8; ++k4) {
            const float4 w4 = *reinterpret_cast<const float4*>(&W[WT_V2 + k4*128 + o32*4]);
            STEP8(acc, X_HV + k4*84, w4, hh);
        }
        #pragma unroll
        for (int p = 0; p < 8; ++p) {
            const int idx = X_X2 + (o32>>2)*84 + (hh*8+p)*4 + (o32&3);
            Sf[idx] += eluf(acc[p]);
        }
    }

    // ================= vis channel 33 : lane=(p,q) =================
    {
        const int p = lane >> 2, q = lane & 3;
        float a = 0.f;
        #pragma unroll
        for (int j = 0; j < 8; ++j) {
            const int k = q*8 + j;
            a = fmaf(Sf[X_HV + (k>>2)*84 + p*4 + (k&3)], vis_w2[k*33 + 32], a);
        }
        a += __shfl_xor(a, 1); a += __shfl_xor(a, 2);
        if (q == 0)
            Sf[SC_V1 + p] = sigmf(eluf(a + vis_b2[32])) * Sf[SC_MASK + p];
    }

    // ================= v2 layer1 (x*vis1 hoisted) -> hv (reuse) =================
    {
        float acc[8];
        #pragma unroll
        for (int p = 0; p < 8; ++p) acc[p] = 0.f;
        #pragma unroll 1
        for (int k4 = 0; k4 < 8; ++k4) {
            const float4 w4 = *reinterpret_cast<const float4*>(&W[WT_U1 + k4*128 + o32*4]);
            STEP8(acc, X_X2 + k4*84, w4, hh);
        }
        const float bb = v2_b1[o32];
        #pragma unroll
        for (int p = 0; p < 8; ++p)
            Sf[X_HV + (o32>>2)*84 + (hh*8+p)*4 + (o32&3)] =
                eluf(fmaf(acc[p], Sf[SC_V1 + hh*8 + p], bb));
    }

    // ================= v2 layer2 -> vis2 : lane=(p,q) =================
    {
        const int p = lane >> 2, q = lane & 3;
        float a = 0.f;
        #pragma unroll
        for (int j = 0; j < 8; ++j) {
            const int k = q*8 + j;
            a = fmaf(Sf[X_HV + (k>>2)*84 + p*4 + (k&3)], v2_w2[k], a);
        }
        a += __shfl_xor(a, 1); a += __shfl_xor(a, 2);
        if (q == 0)
            Sf[SC_V2 + p] = sigmf(a + v2_b2[0]) * Sf[SC_MASK + p];
    }

    // ================= final fmv + gmax -> out : lane=(rs,c) =================
    {
        const int rs = lane >> 5, c = lane & 31;
        float vv[8], xs[8];
        #pragma unroll
        for (int p = 0; p < 8; ++p) {
            vv[p] = Sf[SC_V2 + rs*8 + p];
            xs[p] = Sf[X_X2 + (c>>2)*84 + (rs*8+p)*4 + (c&3)];
        }
        float Vs = 0.f;
        #pragma unroll
        for (int p = 0; p < 8; ++p) Vs += vv[p];
        const float inv = 1.f / (Vs + 1e-8f);
        float m = 0.f;
        #pragma unroll
        for (int p = 0; p < 8; ++p) m = fmaf(vv[p]*inv, xs[p], m);
        float var = 0.f;
        #pragma unroll
        for (int p = 0; p < 8; ++p) {
            const float d = xs[p] - m;
            var = fmaf(vv[p]*inv*d, d, var);
        }
        const size_t ob = b*128 + (size_t)rs*64;
        out[ob + c]      = m   + Sf[X_GMX + rs*64 + c];
        out[ob + 32 + c] = var + Sf[X_GMX + rs*64 + 32 + c];
    }
}

extern "C" void kernel_launch(void* const* d_in, const int* in_sizes, int n_in,
                              void* d_out, int out_size, void* d_ws, size_t ws_size,
                              hipStream_t stream) {
    const float* g_rgb   = (const float*)d_in[0];
    const float* g_nr    = (const float*)d_in[1];
    const float* g_rd    = (const float*)d_in[2];
    const float* g_mask  = (const float*)d_in[3];
    // d_in[4] que_pts, d_in[5] que_dir: unused by the reference
    const float* rd_w1   = (const float*)d_in[6];
    const float* rd_b1   = (const float*)d_in[7];
    const float* rd_w2   = (const float*)d_in[8];
    const float* rd_b2   = (const float*)d_in[9];
    const float* rf_w1   = (const float*)d_in[10];
    const float* rf_b1   = (const float*)d_in[11];
    const float* rf_w2   = (const float*)d_in[12];
    const float* rf_b2   = (const float*)d_in[13];
    const float* nr_w1   = (const float*)d_in[14];
    const float* nr_b1   = (const float*)d_in[15];
    const float* nr_w2   = (const float*)d_in[16];
    const float* nr_b2   = (const float*)d_in[17];
    const float* base_w1 = (const float*)d_in[18];
    const float* base_b1 = (const float*)d_in[19];
    const float* base_w2 = (const float*)d_in[20];
    const float* base_b2 = (const float*)d_in[21];
    const float* vis_w1  = (const float*)d_in[22];
    const float* vis_b1  = (const float*)d_in[23];
    const float* vis_w2  = (const float*)d_in[24];
    const float* vis_b2  = (const float*)d_in[25];
    const float* v2_w1   = (const float*)d_in[26];
    const float* v2_b1   = (const float*)d_in[27];
    const float* v2_w2   = (const float*)d_in[28];
    const float* v2_b2   = (const float*)d_in[29];
    float* ws  = (float*)d_ws;
    float* out = (float*)d_out;

    hipLaunchKernelGGL(transpose_w, dim3((WT_TOT + 255)/256), dim3(256), 0, stream,
                       rf_w1, rf_w2, rd_w2, base_w1, base_w2, vis_w1, vis_w2, v2_w1, ws);

    hipLaunchKernelGGL(nerf_main, dim3(NBLK), dim3(64), 0, stream,
        g_rgb, g_nr, g_rd, g_mask,
        rd_w1, rd_b1, rd_b2,
        rf_b1, rf_b2,
        nr_w1, nr_b1, nr_w2, nr_b2,
        base_b1, base_b2,
        vis_b1, vis_w2, vis_b2,
        v2_b1, v2_w2, v2_b2,
        ws, out);
}